// Round 2
// baseline (201.427 us; speedup 1.0000x reference)
//
#include <hip/hip_runtime.h>
#include <stdint.h>

#define BB 2
#define HH 16
#define TT 2048
#define DD 64
#define NHASH 4
#define NHALF 32   // num_buckets/2

// ---------------- Phase 1: compute packed bucket words ----------------
// grid: BB*HH*(TT/64) blocks of 256 threads. Block handles (b,h, 64 t's).
// words[bh*TT + t] = bucket0 | bucket1<<8 | bucket2<<16 | bucket3<<24
__global__ __launch_bounds__(256) void lsh_buckets_kernel(
    const float* __restrict__ hs,    // [BB, TT, HH*DD]
    const float* __restrict__ rot,   // [HH, DD, NHASH, NHALF]
    uint32_t* __restrict__ words)    // [BB*HH*TT]
{
    __shared__ float rot_lds[DD * NHASH * NHALF];  // 8192 f32 = 32 KiB
    __shared__ float v_lds[64 * DD];               // 4096 f32 = 16 KiB
    __shared__ uint32_t bkt_lds[64][NHASH];        // 1 KiB

    const int blk  = blockIdx.x;
    const int bh   = blk >> 5;        // / (TT/64)
    const int tblk = blk & 31;
    const int b    = bh >> 4;         // / HH
    const int h    = bh & 15;
    const int t0   = tblk * 64;
    const int tid  = threadIdx.x;

    // stage rotations for this head: 8192 floats = 2048 float4
    {
        const float4* src = (const float4*)(rot + (size_t)h * (DD * NHASH * NHALF));
        float4* dst = (float4*)rot_lds;
        for (int k = tid; k < 2048; k += 256) dst[k] = src[k];
    }
    // stage v tile: 64 t x 64 d = 1024 float4
    {
        for (int k = tid; k < 1024; k += 256) {
            int t  = k >> 4;       // 16 float4 per t
            int d4 = k & 15;
            const float4* src = (const float4*)(hs + ((size_t)(b * TT + t0 + t)) * (HH * DD) + h * DD);
            ((float4*)(v_lds + t * DD))[d4] = src[d4];
        }
    }
    __syncthreads();

    const int wave  = tid >> 6;
    const int lane  = tid & 63;
    const int r     = lane & 31;
    const int nhalf = lane >> 5;

    #pragma unroll
    for (int nn = 0; nn < 2; ++nn) {
        const int n = nn * 2 + nhalf;
        // pull this lane's rotation column into f64 registers (128 VGPRs)
        double rotd[DD];
        #pragma unroll
        for (int d = 0; d < DD; ++d)
            rotd[d] = (double)rot_lds[(d * NHASH + n) * NHALF + r];

        for (int k = 0; k < 16; ++k) {
            const int t = wave * 16 + k;
            const float* v = v_lds + t * DD;
            // f64 dot with 4 partial accumulators for ILP (order-insensitive at f64)
            double a0 = 0.0, a1 = 0.0, a2 = 0.0, a3 = 0.0;
            #pragma unroll
            for (int d = 0; d < DD; d += 4) {
                a0 += (double)v[d + 0] * rotd[d + 0];
                a1 += (double)v[d + 1] * rotd[d + 1];
                a2 += (double)v[d + 2] * rotd[d + 2];
                a3 += (double)v[d + 3] * rotd[d + 3];
            }
            float f = (float)((a0 + a1) + (a2 + a3));

            // 32-lane max/argmax and min/argmin with first-index tie-break
            float fmx = f; int imx = r;
            float fmn = f; int imn = r;
            #pragma unroll
            for (int off = 1; off < 32; off <<= 1) {
                float pfx = __shfl_xor(fmx, off, 32);
                int   pix = __shfl_xor(imx, off, 32);
                float pfn = __shfl_xor(fmn, off, 32);
                int   pin = __shfl_xor(imn, off, 32);
                if (pfx > fmx || (pfx == fmx && pix < imx)) { fmx = pfx; imx = pix; }
                if (pfn < fmn || (pfn == fmn && pin < imn)) { fmn = pfn; imn = pin; }
            }
            if (r == 0) {
                // argmax over concat(x,-x): x-half wins ties (earlier indices)
                uint32_t bucket = (fmx >= -fmn) ? (uint32_t)imx : (uint32_t)(32 + imn);
                bkt_lds[t][n] = bucket;
            }
        }
    }
    __syncthreads();

    if (tid < 64) {
        uint32_t w = bkt_lds[tid][0]
                   | (bkt_lds[tid][1] << 8)
                   | (bkt_lds[tid][2] << 16)
                   | (bkt_lds[tid][3] << 24);
        words[(size_t)bh * TT + t0 + tid] = w;
    }
}

// ---------------- Phase 2: materialize the [B,H,T,T] mask (int32 0/1) ----------------
// m[bh][i][j] = any of the 4 bucket bytes equal  ->  1 else 0
__global__ __launch_bounds__(256) void lsh_mask_kernel(
    const uint32_t* __restrict__ words,  // [BB*HH*TT]
    uint4* __restrict__ out)             // BB*HH*TT*TT/4 uint4 (int32 mask)
{
    const uint32_t total4 = (uint32_t)(BB * HH) * TT * (TT / 4);  // 33,554,432
    const uint32_t stride = gridDim.x * blockDim.x;
    for (uint32_t idx = blockIdx.x * blockDim.x + threadIdx.x; idx < total4; idx += stride) {
        const uint32_t o  = idx << 2;             // flat element index (fits u32)
        const uint32_t bh = o >> 22;              // / (TT*TT)
        const uint32_t i  = (o >> 11) & (TT - 1);
        const uint32_t j0 = o & (TT - 1);         // multiple of 4
        const uint32_t wi = words[(bh << 11) + i];
        const uint4 wj = *(const uint4*)(words + (bh << 11) + j0);
        uint4 res;
        uint32_t x;
        x = wi ^ wj.x; res.x = ((x - 0x01010101u) & ~x & 0x80808080u) ? 1u : 0u;
        x = wi ^ wj.y; res.y = ((x - 0x01010101u) & ~x & 0x80808080u) ? 1u : 0u;
        x = wi ^ wj.z; res.z = ((x - 0x01010101u) & ~x & 0x80808080u) ? 1u : 0u;
        x = wi ^ wj.w; res.w = ((x - 0x01010101u) & ~x & 0x80808080u) ? 1u : 0u;
        out[idx] = res;
    }
}

extern "C" void kernel_launch(void* const* d_in, const int* in_sizes, int n_in,
                              void* d_out, int out_size, void* d_ws, size_t ws_size,
                              hipStream_t stream) {
    const float* hs  = (const float*)d_in[0];   // [2, 2048, 1024] f32
    const float* rot = (const float*)d_in[1];   // [16, 64, 4, 32] f32
    uint32_t* words  = (uint32_t*)d_ws;         // needs BB*HH*TT*4 = 1 MiB

    lsh_buckets_kernel<<<BB * HH * (TT / 64), 256, 0, stream>>>(hs, rot, words);
    lsh_mask_kernel<<<2048, 256, 0, stream>>>(words, (uint4*)d_out);
}

// Round 3
// 153.743 us; speedup vs baseline: 1.3102x; 1.3102x over previous
//
#include <hip/hip_runtime.h>
#include <stdint.h>

#define BB 2
#define HH 16
#define TT 2048
#define DD 64
#define NHASH 4
#define NHALF 32   // num_buckets/2

// ---------------- Phase 1: compute packed bucket words ----------------
// grid: BB*HH*(TT/64) = 1024 blocks x 256 threads.
// wave = hash n (4 waves), lane = token offset (64 t's per block).
// Lane-local dot products in f64, f32-compare argmax with first-index
// tie-break (matches numpy's fp32 argmax semantics; verified absmax=0 in r2).
__global__ __launch_bounds__(256, 2) void lsh_buckets_kernel(
    const float* __restrict__ hs,    // [BB, TT, HH*DD]
    const float* __restrict__ rot,   // [HH, DD, NHASH, NHALF]
    uint32_t* __restrict__ words)    // [BB*HH*TT]
{
    __shared__ double rot_d[NHASH * NHALF * DD];   // [n][r][d], exactly 64 KiB

    const int blk  = blockIdx.x;
    const int bh   = blk >> 5;        // / (TT/64)
    const int tblk = blk & 31;
    const int b    = bh >> 4;         // / HH
    const int h    = bh & 15;
    const int t0   = tblk * 64;
    const int tid  = threadIdx.x;
    const int n    = tid >> 6;        // wave id = hash index
    const int lt   = tid & 63;        // lane = token offset

    // stage rotations for this head, f32 -> f64, transpose [d][nr] -> [nr][d]
    // (consecutive threads write consecutive LDS addrs: conflict-free; the
    //  strided global reads hit L1/L2 — rot head block is only 32 KiB)
    {
        const float* rh = rot + (size_t)h * (DD * NHASH * NHALF);
        for (int k = tid; k < NHASH * NHALF * DD; k += 256) {
            const int d  = k & 63;
            const int nr = k >> 6;
            rot_d[k] = (double)rh[d * (NHASH * NHALF) + nr];
        }
    }

    // load this lane's v row into f64 registers (256 B contiguous per lane)
    const int t = t0 + lt;
    const float* vp = hs + ((size_t)(b * TT + t)) * (HH * DD) + h * DD;
    double vd[DD];
    #pragma unroll
    for (int d4 = 0; d4 < 16; ++d4) {
        const float4 f = ((const float4*)vp)[d4];
        vd[d4 * 4 + 0] = (double)f.x;
        vd[d4 * 4 + 1] = (double)f.y;
        vd[d4 * 4 + 2] = (double)f.z;
        vd[d4 * 4 + 3] = (double)f.w;
    }
    __syncthreads();

    // 32 dot products, lane-local running argmax/argmin (f32 compare,
    // ascending r with strict inequality = first-occurrence tie-break)
    const double* cb = rot_d + n * (NHALF * DD);
    float fmx = -INFINITY; int imx = 0;
    float fmn =  INFINITY; int imn = 0;
    for (int r = 0; r < NHALF; ++r) {
        const double* c = cb + r * DD;   // wave-uniform -> broadcast reads
        double a0 = 0.0, a1 = 0.0, a2 = 0.0, a3 = 0.0;
        #pragma unroll
        for (int d = 0; d < DD; d += 4) {
            a0 += vd[d + 0] * c[d + 0];
            a1 += vd[d + 1] * c[d + 1];
            a2 += vd[d + 2] * c[d + 2];
            a3 += vd[d + 3] * c[d + 3];
        }
        const float f = (float)((a0 + a1) + (a2 + a3));
        if (f > fmx) { fmx = f; imx = r; }
        if (f < fmn) { fmn = f; imn = r; }
    }
    const uint32_t bucket = (fmx >= -fmn) ? (uint32_t)imx : (uint32_t)(NHALF + imn);

    // exchange bucket bytes via LDS (alias rot_d space — all reads done)
    __syncthreads();
    uint32_t* bk = (uint32_t*)rot_d;    // [NHASH][64]
    bk[n * 64 + lt] = bucket;
    __syncthreads();
    if (tid < 64) {
        words[(size_t)bh * TT + t0 + tid] = bk[0 * 64 + tid]
                                          | (bk[1 * 64 + tid] << 8)
                                          | (bk[2 * 64 + tid] << 16)
                                          | (bk[3 * 64 + tid] << 24);
    }
}

// ---------------- Phase 2: materialize the [B,H,T,T] mask (int32 0/1) ----------------
// block = (bh, 8 rows). Each thread holds its 2 uint4 of bucket words and
// streams 8 rows of coalesced 16B stores.
#define ROWS 8
__device__ __forceinline__ uint32_t eq_any_byte(uint32_t a, uint32_t b) {
    const uint32_t x = a ^ b;
    return ((x - 0x01010101u) & ~x & 0x80808080u) ? 1u : 0u;
}

__global__ __launch_bounds__(256) void lsh_mask_kernel(
    const uint32_t* __restrict__ words,  // [BB*HH*TT]
    uint4* __restrict__ out)             // [BB*HH*TT][TT/4]
{
    const int bh  = blockIdx.x >> 8;            // TT/ROWS = 256 blocks per bh
    const int i0  = (blockIdx.x & 255) * ROWS;
    const int tid = threadIdx.x;
    const uint32_t* wrow = words + (bh << 11);

    const uint4 wj0 = ((const uint4*)wrow)[tid];        // j = tid*4
    const uint4 wj1 = ((const uint4*)wrow)[tid + 256];  // j = tid*4 + 1024

    #pragma unroll
    for (int k = 0; k < ROWS; ++k) {
        const uint32_t wi = wrow[i0 + k];
        uint4 r0, r1;
        r0.x = eq_any_byte(wi, wj0.x); r0.y = eq_any_byte(wi, wj0.y);
        r0.z = eq_any_byte(wi, wj0.z); r0.w = eq_any_byte(wi, wj0.w);
        r1.x = eq_any_byte(wi, wj1.x); r1.y = eq_any_byte(wi, wj1.y);
        r1.z = eq_any_byte(wi, wj1.z); r1.w = eq_any_byte(wi, wj1.w);
        uint4* op = out + (((size_t)((bh << 11) + i0 + k)) << 9);
        op[tid]       = r0;
        op[tid + 256] = r1;
    }
}

extern "C" void kernel_launch(void* const* d_in, const int* in_sizes, int n_in,
                              void* d_out, int out_size, void* d_ws, size_t ws_size,
                              hipStream_t stream) {
    const float* hs  = (const float*)d_in[0];   // [2, 2048, 1024] f32
    const float* rot = (const float*)d_in[1];   // [16, 64, 4, 32] f32
    uint32_t* words  = (uint32_t*)d_ws;         // needs BB*HH*TT*4 = 512 KiB

    lsh_buckets_kernel<<<BB * HH * (TT / 64), 256, 0, stream>>>(hs, rot, words);
    lsh_mask_kernel<<<BB * HH * (TT / ROWS), 256, 0, stream>>>(words, (uint4*)d_out);
}

// Round 4
// 133.753 us; speedup vs baseline: 1.5060x; 1.1495x over previous
//
#include <hip/hip_runtime.h>
#include <stdint.h>

#define BB 2
#define HH 16
#define TT 2048
#define DD 64
#define NHASH 4
#define NHALF 32   // num_buckets/2

// ---------------- Phase 1: compute packed bucket words ----------------
// grid: BB*HH*(TT/64) = 1024 blocks x 256 threads (4 waves).
// wave = hash n; lane = (tg = lane>>3, rg = lane&7) owns an 8-token x 4-r
// f64 accumulator tile. v and rot staged in LDS as f32 with XOR swizzle
// (slot = d4 ^ rowgroup) so tile reads are bank-conflict-free.
// f64 accumulation matches the (f64) np reference; f32 compares with
// first-index tie-break matched exactly in rounds 2-3 (absmax 0).
__global__ __launch_bounds__(256, 2) void lsh_buckets_kernel(
    const float* __restrict__ hs,    // [BB, TT, HH*DD]
    const float* __restrict__ rot,   // [HH, DD, NHASH, NHALF]
    uint32_t* __restrict__ words)    // [BB*HH*TT]
{
    __shared__ uint32_t lds[12288];            // 48 KiB
    float4* v4 = (float4*)lds;                 // [64 t][16 slots]   (16 KiB)
    float4* r4 = (float4*)(lds + 4096);        // [4 n][32 r][16 slots] (32 KiB)

    const int blk  = blockIdx.x;
    const int bh   = blk >> 5;        // / (TT/64)
    const int tblk = blk & 31;
    const int b    = bh >> 4;
    const int h    = bh & 15;
    const int t0   = tblk * 64;
    const int tid  = threadIdx.x;
    const int n    = tid >> 6;        // wave = hash
    const int lane = tid & 63;
    const int tg   = lane >> 3;       // token group (8 tokens)
    const int rg   = lane & 7;        // r group (4 r's)

    // ---- stage v tile: [64 t][64 d] f32, slot = d4 ^ (t>>3) ----
    #pragma unroll
    for (int p = 0; p < 4; ++p) {
        const int k  = tid + p * 256;       // 0..1023 float4s
        const int t  = k >> 4;
        const int d4 = k & 15;
        const float4 f = ((const float4*)(hs + ((size_t)(b * TT + t0 + t)) * (HH * DD) + h * DD))[d4];
        v4[t * 16 + (d4 ^ (t >> 3))] = f;
    }
    // ---- stage rot: [4 n][32 r][64 d] f32, slot = d4 ^ (r>>2) ----
    {
        const float* rh = rot + (size_t)h * (DD * NHASH * NHALF);
        float* rf = (float*)r4;
        #pragma unroll
        for (int p = 0; p < 32; ++p) {
            const int g  = tid + p * 256;   // global idx: d*128 + n*32 + r (coalesced)
            const int d  = g >> 7;
            const int nr = g & 127;
            const int nn = nr >> 5;
            const int r  = nr & 31;
            const int slot = (d >> 2) ^ (r >> 2);
            rf[((nn * 32 + r) * 16 + slot) * 4 + (d & 3)] = rh[g];
        }
    }
    __syncthreads();

    // ---- K loop: acc[i][j] (t = tg*8+i, r = rg*4+j), f64 ----
    double acc[8][4];
    #pragma unroll
    for (int i = 0; i < 8; ++i)
        #pragma unroll
        for (int j = 0; j < 4; ++j) acc[i][j] = 0.0;

    const int vbase = tg * 8 * 16;                 // float4 index of first own token row
    const int rbase = (n * 32 + rg * 4) * 16;      // float4 index of first own r row

    for (int s = 0; s < 16; ++s) {                 // d = s*4 .. s*4+3
        double rd[4][4];
        #pragma unroll
        for (int j = 0; j < 4; ++j) {
            const float4 rf = r4[rbase + j * 16 + (s ^ rg)];
            rd[j][0] = (double)rf.x; rd[j][1] = (double)rf.y;
            rd[j][2] = (double)rf.z; rd[j][3] = (double)rf.w;
        }
        #pragma unroll
        for (int i = 0; i < 8; ++i) {
            const float4 vf = v4[vbase + i * 16 + (s ^ tg)];
            const double v0 = (double)vf.x, v1 = (double)vf.y;
            const double v2 = (double)vf.z, v3 = (double)vf.w;
            #pragma unroll
            for (int j = 0; j < 4; ++j) {
                acc[i][j] += v0 * rd[j][0];
                acc[i][j] += v1 * rd[j][1];
                acc[i][j] += v2 * rd[j][2];
                acc[i][j] += v3 * rd[j][3];
            }
        }
    }

    // ---- epilogue: argmax/argmin over r per (n,t) ----
    __syncthreads();   // all LDS reads done; alias lds for partials
    float*    vmaxL = (float*)lds;            // [4][64][9]
    float*    vminL = (float*)(lds + 2304);
    uint32_t* imaxL = lds + 4608;
    uint32_t* iminL = lds + 6912;
    uint32_t* bkt   = lds + 9216;             // [4][64]

    #pragma unroll
    for (int i = 0; i < 8; ++i) {
        const int t = tg * 8 + i;
        float fmx = -INFINITY; int imx = 0;
        float fmn =  INFINITY; int imn = 0;
        #pragma unroll
        for (int j = 0; j < 4; ++j) {
            const float f = (float)acc[i][j];
            const int   r = rg * 4 + j;
            if (f > fmx) { fmx = f; imx = r; }
            if (f < fmn) { fmn = f; imn = r; }
        }
        const int o = (n * 64 + t) * 9 + rg;
        vmaxL[o] = fmx; vminL[o] = fmn;
        imaxL[o] = (uint32_t)imx; iminL[o] = (uint32_t)imn;
    }
    __syncthreads();
    {
        const int nn = tid >> 6;
        const int t  = tid & 63;
        float fmx = -INFINITY; int imx = 0;
        float fmn =  INFINITY; int imn = 0;
        #pragma unroll
        for (int g = 0; g < 8; ++g) {     // rg ascending -> r ascending: first-index tie-break
            const int o = (nn * 64 + t) * 9 + g;
            const float fx = vmaxL[o];
            const float fn = vminL[o];
            if (fx > fmx) { fmx = fx; imx = (int)imaxL[o]; }
            if (fn < fmn) { fmn = fn; imn = (int)iminL[o]; }
        }
        const uint32_t bucket = (fmx >= -fmn) ? (uint32_t)imx : (uint32_t)(NHALF + imn);
        bkt[nn * 64 + t] = bucket;
    }
    __syncthreads();
    if (tid < 64) {
        words[(size_t)bh * TT + t0 + tid] = bkt[tid]
                                          | (bkt[64  + tid] << 8)
                                          | (bkt[128 + tid] << 16)
                                          | (bkt[192 + tid] << 24);
    }
}

// ---------------- Phase 2: materialize the [B,H,T,T] mask (int32 0/1) ----------------
#define ROWS 8
__device__ __forceinline__ uint32_t eq_any_byte(uint32_t a, uint32_t b) {
    const uint32_t x = a ^ b;
    return ((x - 0x01010101u) & ~x & 0x80808080u) ? 1u : 0u;
}

__global__ __launch_bounds__(256) void lsh_mask_kernel(
    const uint32_t* __restrict__ words,  // [BB*HH*TT]
    uint4* __restrict__ out)             // [BB*HH*TT][TT/4]
{
    const int bh  = blockIdx.x >> 8;            // TT/ROWS = 256 blocks per bh
    const int i0  = (blockIdx.x & 255) * ROWS;
    const int tid = threadIdx.x;
    const uint32_t* wrow = words + (bh << 11);

    const uint4 wj0 = ((const uint4*)wrow)[tid];        // j = tid*4
    const uint4 wj1 = ((const uint4*)wrow)[tid + 256];  // j = tid*4 + 1024

    #pragma unroll
    for (int k = 0; k < ROWS; ++k) {
        const uint32_t wi = wrow[i0 + k];
        uint4 r0, r1;
        r0.x = eq_any_byte(wi, wj0.x); r0.y = eq_any_byte(wi, wj0.y);
        r0.z = eq_any_byte(wi, wj0.z); r0.w = eq_any_byte(wi, wj0.w);
        r1.x = eq_any_byte(wi, wj1.x); r1.y = eq_any_byte(wi, wj1.y);
        r1.z = eq_any_byte(wi, wj1.z); r1.w = eq_any_byte(wi, wj1.w);
        uint4* op = out + (((size_t)((bh << 11) + i0 + k)) << 9);
        op[tid]       = r0;
        op[tid + 256] = r1;
    }
}

extern "C" void kernel_launch(void* const* d_in, const int* in_sizes, int n_in,
                              void* d_out, int out_size, void* d_ws, size_t ws_size,
                              hipStream_t stream) {
    const float* hs  = (const float*)d_in[0];   // [2, 2048, 1024] f32
    const float* rot = (const float*)d_in[1];   // [16, 64, 4, 32] f32
    uint32_t* words  = (uint32_t*)d_ws;         // needs BB*HH*TT*4 = 512 KiB

    lsh_buckets_kernel<<<BB * HH * (TT / 64), 256, 0, stream>>>(hs, rot, words);
    lsh_mask_kernel<<<BB * HH * (TT / ROWS), 256, 0, stream>>>(words, (uint4*)d_out);
}